// Round 1
// baseline (330.149 us; speedup 1.0000x reference)
//
#include <hip/hip_runtime.h>

// MoE SwiGLU gather, bf16 MFMA grouped GEMM. R4: latency-stall attack.
//  - K-chunk 64 (was 32): half the barriers, 2x bytes in flight.
//  - LDS-only barriers (s_waitcnt lgkmcnt(0) + raw s_barrier): weight
//    prefetch for chunk t+2 stays in flight ACROSS the barrier (T3/T4).
//  - A operand loaded per-lane direct global->reg (k-contiguous frag):
//    no LDS staging for A, B-only LDS double buffer (36KB / 18KB).
// Counters said latency-bound (Mfma 6%, VALU 13%, HBM 11%, occ 44%):
// every pipe idle -> kill the vmcnt(0) drains, not the arithmetic.

#define NEXP 8
#define HDIM 2816
#define DDIM 1024
#define NPAIR 1024

typedef unsigned int uint;
typedef unsigned short ushort;
typedef __attribute__((ext_vector_type(8))) short bf16x8;
typedef __attribute__((ext_vector_type(4))) float fvec4;
typedef __attribute__((ext_vector_type(4))) uint uvec4;

__device__ __forceinline__ ushort f2bf(float f) {
    uint u = __builtin_bit_cast(uint, f);
    u += 0x7fff + ((u >> 16) & 1);          // RTNE
    return (ushort)(u >> 16);
}
__device__ __forceinline__ uint pack2(float lo, float hi) {
    return (uint)f2bf(lo) | ((uint)f2bf(hi) << 16);
}
__device__ __forceinline__ uvec4 pack8(fvec4 a, fvec4 b) {
    uvec4 v;
    v.x = pack2(a.x, a.y); v.y = pack2(a.z, a.w);
    v.z = pack2(b.x, b.y); v.w = pack2(b.z, b.w);
    return v;
}

// LDS-only workgroup barrier: drains DS ops for cross-wave visibility but
// leaves global loads in flight (unlike __syncthreads' vmcnt(0) drain).
__device__ __forceinline__ void wg_sync_lds() {
    __builtin_amdgcn_sched_barrier(0);
    asm volatile("s_waitcnt lgkmcnt(0)" ::: "memory");
    __builtin_amdgcn_s_barrier();
    __builtin_amdgcn_sched_barrier(0);
}

// ws: [0] counts 32B | [1024] lists 32KB | [65536] hbuf bf16 5.77MB
__global__ __launch_bounds__(1024) void route_kernel(const int* __restrict__ idx,
                                                     int* __restrict__ counts,
                                                     int* __restrict__ lists) {
    int p = threadIdx.x;
    if (p < NEXP) counts[p] = 0;     // ws re-poisoned every call
    __syncthreads();
    int e = idx[p];
    int pos = atomicAdd(&counts[e], 1);
    lists[e * NPAIR + pos] = p;
}

// ---------------- Phase 1: hbuf[p,h] = silu(x·w1)*(x·w3) ----------------
// grid (8, 44, 8) = (expert, 64-h tile, 128-m tile), block 512 (8 waves).
// K-chunk 64, 16 chunks. B1/B3 double-buffered in LDS, depth-2 register
// prefetch; A frags read per-lane direct from x (L2-resident, gathered).
#define LDB 68                 // 64 + 4 bf16 pad
#define NCH1 (DDIM / 64)       // 16

__global__ __launch_bounds__(512, 3) void h_mfma(const float* __restrict__ x,
                       const float* __restrict__ w1,
                       const float* __restrict__ w3,
                       const int* __restrict__ counts,
                       const int* __restrict__ lists,
                       ushort* __restrict__ hb) {
    const int e = blockIdx.x;
    const int cnt = counts[e];
    const int m0 = blockIdx.z * 128;
    if (m0 >= cnt) return;
    const int h0 = blockIdx.y * 64;

    __shared__ ushort sB1[2][64 * LDB];
    __shared__ ushort sB3[2][64 * LDB];
    __shared__ int sTok[128];
    __shared__ int sPairS[128];

    const int tid = threadIdx.x;
    if (tid < 128) {
        int m = m0 + tid;
        int mc = (m < cnt) ? m : (cnt - 1);
        int p = lists[e * NPAIR + mc];
        sTok[tid] = p >> 1;                 // TOPK=2
        sPairS[tid] = (m < cnt) ? p : -1;
    }

    const int w = tid >> 6;
    const int lane = tid & 63;
    const int l16 = lane & 15;
    const int quad = lane >> 4;

    // B staging role: 8 threads per h-row, 32B (8 fp32) each.
    const int brow = tid >> 3;              // 0..63
    const int bc = (tid & 7) * 8;           // k-col base
    const float* pB1 = w1 + (size_t)e * HDIM * DDIM + (size_t)(h0 + brow) * DDIM + bc;
    const float* pB3 = w3 + (size_t)e * HDIM * DDIM + (size_t)(h0 + brow) * DDIM + bc;

    fvec4 pf[2][4];    // [set][b1lo,b1hi,b3lo,b3hi] — indices literal via unroll

#define P1_ISSUE(S, KC) do { \
    const float* q1 = pB1 + (KC) * 64; \
    const float* q3 = pB3 + (KC) * 64; \
    pf[S][0] = *(const fvec4*)q1;  pf[S][1] = *(const fvec4*)(q1 + 4); \
    pf[S][2] = *(const fvec4*)q3;  pf[S][3] = *(const fvec4*)(q3 + 4); \
} while (0)

#define P1_STAGE(S, B) do { \
    *(uvec4*)&sB1[B][brow * LDB + bc] = pack8(pf[S][0], pf[S][1]); \
    *(uvec4*)&sB3[B][brow * LDB + bc] = pack8(pf[S][2], pf[S][3]); \
} while (0)

    P1_ISSUE(0, 0);
    P1_ISSUE(1, 1);
    wg_sync_lds();                          // sTok/sPairS visible; B loads fly on
    const float* xA = x + (size_t)sTok[w * 16 + l16] * DDIM + quad * 8;

    fvec4 acc1[4], acc3[4];
    #pragma unroll
    for (int i = 0; i < 4; ++i) { acc1[i] = (fvec4)0.f; acc3[i] = (fvec4)0.f; }

    P1_STAGE(0, 0);                         // compiler vmcnt waits set0 only
    wg_sync_lds();

    // iter T (CUR=T&1): LDS buf CUR holds chunk T; set CUR^1 holds chunk T+1
    // (possibly in flight); set CUR is free -> issue chunk T+2 into it.
    // A loads issued FIRST so their vmcnt wait never drains set CUR.
#define P1_BODY(T, CUR) do { \
    const int kA = (T) * 64; \
    fvec4 a0 = *(const fvec4*)(xA + kA); \
    fvec4 a1 = *(const fvec4*)(xA + kA + 4); \
    fvec4 a2 = *(const fvec4*)(xA + kA + 32); \
    fvec4 a3 = *(const fvec4*)(xA + kA + 36); \
    if ((T) + 2 < NCH1) P1_ISSUE(CUR, (T) + 2); \
    bf16x8 af0 = __builtin_bit_cast(bf16x8, pack8(a0, a1)); \
    bf16x8 af1 = __builtin_bit_cast(bf16x8, pack8(a2, a3)); \
    _Pragma("unroll") \
    for (int ni = 0; ni < 4; ++ni) { \
        const int ro = (ni * 16 + l16) * LDB + quad * 8; \
        bf16x8 b10 = *(const bf16x8*)&sB1[CUR][ro]; \
        bf16x8 b30 = *(const bf16x8*)&sB3[CUR][ro]; \
        bf16x8 b11 = *(const bf16x8*)&sB1[CUR][ro + 32]; \
        bf16x8 b31 = *(const bf16x8*)&sB3[CUR][ro + 32]; \
        acc1[ni] = __builtin_amdgcn_mfma_f32_16x16x32_bf16(af0, b10, acc1[ni], 0, 0, 0); \
        acc3[ni] = __builtin_amdgcn_mfma_f32_16x16x32_bf16(af0, b30, acc3[ni], 0, 0, 0); \
        acc1[ni] = __builtin_amdgcn_mfma_f32_16x16x32_bf16(af1, b11, acc1[ni], 0, 0, 0); \
        acc3[ni] = __builtin_amdgcn_mfma_f32_16x16x32_bf16(af1, b31, acc3[ni], 0, 0, 0); \
    } \
    if ((T) + 1 < NCH1) { \
        P1_STAGE(CUR ^ 1, CUR ^ 1); \
        wg_sync_lds(); \
    } \
} while (0)

    for (int t = 0; t < NCH1; t += 2) {     // NCH1 = 16, even
        P1_BODY(t, 0);
        P1_BODY(t + 1, 1);
    }

    // epilogue: C/D layout col=l16, row=quad*4+r
    #pragma unroll
    for (int r = 0; r < 4; ++r) {
        int m = w * 16 + quad * 4 + r;
        int p = sPairS[m];
        if (p >= 0) {
            size_t base = (size_t)p * HDIM + h0;
            #pragma unroll
            for (int ni = 0; ni < 4; ++ni) {
                float a = acc1[ni][r];
                float g = acc3[ni][r];
                float s = a / (1.f + __expf(-a)) * g;
                hb[base + ni * 16 + l16] = f2bf(s);
            }
        }
    }
}

// ---------------- Phase 2: out[p,d] += hbuf[p,:]·w2[e,:,d] ----------------
// grid (8, 16, 32): (expert, 64-d tile, mblock*4 + splitK). block 512.
// K-chunk 64, 11 chunks per split. B (w2, transposed) double-buffered in
// LDS with depth-2 prefetch; A frags direct from hbuf (bf16, zero-copy).
#define LDB2 68
#define NCH2 ((HDIM / 4) / 64)   // 11

__global__ __launch_bounds__(512, 3) void out_mfma(const float* __restrict__ w2,
                         const int* __restrict__ counts,
                         const int* __restrict__ lists,
                         const ushort* __restrict__ hb,
                         float* __restrict__ out) {
    const int e = blockIdx.x;
    const int cnt = counts[e];
    const int mb = blockIdx.z >> 2;
    const int sk = blockIdx.z & 3;
    const int m0 = mb * 128;
    if (m0 >= cnt) return;
    const int n0 = blockIdx.y * 64;
    const int kbase = sk * (HDIM / 4);      // 704 per split

    __shared__ ushort sB[2][64 * LDB2];
    __shared__ int sPairC[128];
    __shared__ int sPairS[128];

    const int tid = threadIdx.x;
    if (tid < 128) {
        int m = m0 + tid;
        int mc = (m < cnt) ? m : (cnt - 1);
        int p = lists[e * NPAIR + mc];
        sPairC[tid] = p;
        sPairS[tid] = (m < cnt) ? p : -1;
    }

    const int w = tid >> 6;
    const int lane = tid & 63;
    const int l16 = lane & 15;
    const int quad = lane >> 4;
    const int kp = tid >> 4;     // 0..31 k-row pair
    const int n4 = tid & 15;     // float4 group along n

    const float* pW = w2 + (size_t)e * HDIM * DDIM
                         + (size_t)(kbase + 2 * kp) * DDIM + n0 + n4 * 4;

    fvec4 pw[2][2];    // [set][k-row 2kp, 2kp+1]

#define P2_ISSUE(S, KC) do { \
    const float* q = pW + (size_t)(KC) * 64 * DDIM; \
    pw[S][0] = *(const fvec4*)q; \
    pw[S][1] = *(const fvec4*)(q + DDIM); \
} while (0)

#define P2_STAGE(S, B) do { \
    _Pragma("unroll") \
    for (int j = 0; j < 4; ++j) \
        *(uint*)&sB[B][(n4 * 4 + j) * LDB2 + kp * 2] = pack2(pw[S][0][j], pw[S][1][j]); \
} while (0)

    P2_ISSUE(0, 0);
    P2_ISSUE(1, 1);
    wg_sync_lds();                          // pair lists visible
    const ushort* pA = hb + (size_t)sPairC[w * 16 + l16] * HDIM + kbase + quad * 8;

    fvec4 acc[4];
    #pragma unroll
    for (int i = 0; i < 4; ++i) acc[i] = (fvec4)0.f;

    P2_STAGE(0, 0);
    wg_sync_lds();

#define P2_BODY(T, CUR) do { \
    const int kA = (T) * 64; \
    bf16x8 af0 = *(const bf16x8*)(pA + kA); \
    bf16x8 af1 = *(const bf16x8*)(pA + kA + 32); \
    if ((T) + 2 < NCH2) P2_ISSUE(CUR, (T) + 2); \
    _Pragma("unroll") \
    for (int ni = 0; ni < 4; ++ni) { \
        const int ro = (ni * 16 + l16) * LDB2 + quad * 8; \
        bf16x8 b0 = *(const bf16x8*)&sB[CUR][ro]; \
        bf16x8 b1 = *(const bf16x8*)&sB[CUR][ro + 32]; \
        acc[ni] = __builtin_amdgcn_mfma_f32_16x16x32_bf16(af0, b0, acc[ni], 0, 0, 0); \
        acc[ni] = __builtin_amdgcn_mfma_f32_16x16x32_bf16(af1, b1, acc[ni], 0, 0, 0); \
    } \
    if ((T) + 1 < NCH2) { \
        P2_STAGE(CUR ^ 1, CUR ^ 1); \
        wg_sync_lds(); \
    } \
} while (0)

    for (int t = 0; t < NCH2; t += 2) {     // NCH2 = 11, odd
        P2_BODY(t, 0);
        if (t + 1 < NCH2) P2_BODY(t + 1, 1);
    }

    #pragma unroll
    for (int r = 0; r < 4; ++r) {
        int m = w * 16 + quad * 4 + r;
        int p = sPairS[m];
        if (p >= 0) {
            #pragma unroll
            for (int ni = 0; ni < 4; ++ni)
                atomicAdd(&out[(size_t)p * DDIM + n0 + ni * 16 + l16], acc[ni][r]);
        }
    }
}

extern "C" void kernel_launch(void* const* d_in, const int* in_sizes, int n_in,
                              void* d_out, int out_size, void* d_ws, size_t ws_size,
                              hipStream_t stream) {
    const float* x   = (const float*)d_in[0];
    const int*   idx = (const int*)d_in[1];
    const float* w1  = (const float*)d_in[2];
    const float* w2  = (const float*)d_in[3];
    const float* w3  = (const float*)d_in[4];
    float* out = (float*)d_out;

    char* ws = (char*)d_ws;
    int*    counts = (int*)ws;
    int*    lists  = (int*)(ws + 1024);
    ushort* hbuf   = (ushort*)(ws + 65536);

    hipMemsetAsync(out, 0, (size_t)out_size * sizeof(float), stream);
    route_kernel<<<1, NPAIR, 0, stream>>>(idx, counts, lists);
    h_mfma<<<dim3(NEXP, HDIM / 64, NPAIR / 128), 512, 0, stream>>>(
        x, w1, w3, counts, lists, hbuf);
    out_mfma<<<dim3(NEXP, DDIM / 64, (NPAIR / 128) * 4), 512, 0, stream>>>(
        w2, counts, lists, hbuf, out);
}